// Round 2
// baseline (59.811 us; speedup 1.0000x reference)
//
#include <hip/hip_runtime.h>
#include <hip/hip_bf16.h>

// Problem constants (from setup_inputs): x [B,C,T] fp32, out [B,C,T] fp32.
#define B_ 32
#define C_ 256
#define T_ 2048
#define CHUNK 128
#define K_ (T_ / CHUNK)   // 16 chunks per row
#define LOOK 64           // warm-start lookback; v-error halves per step -> bitwise collapse

// Depthwise conv(k=3,pad=1) + BN(inference) + multi-step LIF (tau=2, v_th=1,
// hard reset, detached) + residual. fp32 output. One thread per (row, chunk).
__global__ __launch_bounds__(256) void cpe_lif_kernel(
    const float* __restrict__ x, const float* __restrict__ w,
    const float* __restrict__ cb, const float* __restrict__ gamma,
    const float* __restrict__ beta, const float* __restrict__ rmean,
    const float* __restrict__ rvar, float* __restrict__ out)
{
#pragma clang fp contract(off)   // match np reference rounding op-for-op
    const int u = blockIdx.x * blockDim.x + threadIdx.x;
    const int row = u >> 4;          // / K_
    const int k   = u & (K_ - 1);
    if (row >= B_ * C_) return;
    const int c = row & (C_ - 1);

    // Per-channel constants, mirroring a numpy port op-for-op (all fp32):
    //   s = sqrt(var+eps); r = 1/s; inv = gamma*r; add = beta - mean*inv
    const float w0 = w[c * 3 + 0], w1 = w[c * 3 + 1], w2 = w[c * 3 + 2];
    const float bb = cb[c];
    const float sq  = sqrtf(rvar[c] + 1e-5f);
    const float rs  = 1.0f / sq;
    const float inv = gamma[c] * rs;
    const float add = beta[c] - rmean[c] * inv;

    const float*  xr  = x + (size_t)row * T_;
    const float4* xr4 = (const float4*)xr;
    float* outr = out + (size_t)row * T_;

    const int t0 = k * CHUNK;
    int ts = t0 - LOOK; if (ts < 0) ts = 0;

    float xm1 = (ts == 0) ? 0.0f : xr[ts - 1];  // conv left halo (x[-1] = 0 pad)
    float v = 0.0f;                              // exact for k==0; warm-started else

    const int gBeg = ts >> 3, gEnd = (t0 + CHUNK) >> 3;
    float4 lo = xr4[2 * gBeg], hi = xr4[2 * gBeg + 1];

    for (int g = gBeg; g < gEnd; ++g) {
        float4 nlo, nhi;
        if (g + 1 < (T_ >> 3)) { nlo = xr4[2 * g + 2]; nhi = xr4[2 * g + 3]; }
        else                   { nlo = make_float4(0.f, 0.f, 0.f, 0.f); nhi = nlo; }

        const float xc[9] = {lo.x, lo.y, lo.z, lo.w, hi.x, hi.y, hi.z, hi.w, nlo.x};
        float o[8];

        #pragma unroll
        for (int j = 0; j < 8; ++j) {
            const float x0 = xc[j], xp1 = xc[j + 1];
            float y = w0 * xm1;          // cross-correlation, no kernel flip
            y = y + w1 * x0;
            y = y + w2 * xp1;
            y = y + bb;
            y = y * inv;                 // BN scale
            y = y + add;                 // BN shift
            const float dv = (y - v) * 0.5f;   // (x - v)/tau, tau=2 (*0.5 == /2 bitwise)
            v = v + dv;
            const float s = (v >= 1.0f) ? 1.0f : 0.0f;  // == (v - 1 >= 0) in IEEE
            o[j] = s + x0;                               // spike + residual (fp32)
            v = (v >= 1.0f) ? 0.0f : v;                  // hard reset (v*(1-s))
            xm1 = x0;
        }

        const int tbase = g << 3;
        if (tbase >= t0) {               // lookback region: compute only, no store
            float4* op = reinterpret_cast<float4*>(outr + tbase);
            op[0] = make_float4(o[0], o[1], o[2], o[3]);
            op[1] = make_float4(o[4], o[5], o[6], o[7]);
        }

        lo = nlo; hi = nhi;
    }
}

extern "C" void kernel_launch(void* const* d_in, const int* in_sizes, int n_in,
                              void* d_out, int out_size, void* d_ws, size_t ws_size,
                              hipStream_t stream) {
    const float* x     = (const float*)d_in[0];
    const float* w     = (const float*)d_in[1];
    const float* cb    = (const float*)d_in[2];
    const float* gamma = (const float*)d_in[3];
    const float* beta  = (const float*)d_in[4];
    const float* rmean = (const float*)d_in[5];
    const float* rvar  = (const float*)d_in[6];
    float* out = (float*)d_out;

    const int total  = B_ * C_ * K_;         // 131072 threads
    const int block  = 256;
    const int grid   = (total + block - 1) / block;  // 512 blocks -> 8 waves/CU
    cpe_lif_kernel<<<grid, block, 0, stream>>>(x, w, cb, gamma, beta, rmean, rvar, out);
}

// Round 3
// 44.985 us; speedup vs baseline: 1.3296x; 1.3296x over previous
//
#include <hip/hip_runtime.h>

typedef float f32x4 __attribute__((ext_vector_type(4)));

// Problem constants: x [B,C,T] fp32 -> out [B,C,T] fp32.
#define B_ 32
#define C_ 256
#define T_ 2048
#define CHUNK 128
#define K_ 16          // chunks per row
#define LOOK 64        // warm-start lookback (proven bitwise-exact in R2)

// One thread per (row, chunk). 6 phases x 32 elements = LOOK + CHUNK.
// Triple-buffered register pipeline (2-phase load slack) + full-line
// (128 B) burst stores.

#define STEP(X0, XP1, O) { \
    float y = w0 * xm1;  y = y + w1 * (X0);  y = y + w2 * (XP1); \
    y = y + bb;  y = y * inv;  y = y + add; \
    float dv = (y - v) * 0.5f;  v = v + dv; \
    float s = (v >= 1.0f) ? 1.0f : 0.0f; \
    (O) = s + (X0); \
    v = (v >= 1.0f) ? 0.0f : v; \
    xm1 = (X0); }

#define Q4(BV, NX, O) \
    STEP(BV.x, BV.y, O.x) STEP(BV.y, BV.z, O.y) \
    STEP(BV.z, BV.w, O.z) STEP(BV.w, NX,   O.w)

// compute 32 elems from r0..r7; PEEK = x[tp+32]; optional full-line store burst
#define PHASE32(r0,r1,r2,r3,r4,r5,r6,r7, PEEK, TP, DOSTORE) { \
    f32x4 o0,o1,o2,o3,o4,o5,o6,o7; \
    Q4(r0, r1.x, o0) Q4(r1, r2.x, o1) Q4(r2, r3.x, o2) Q4(r3, r4.x, o3) \
    Q4(r4, r5.x, o4) Q4(r5, r6.x, o5) Q4(r6, r7.x, o6) Q4(r7, PEEK, o7) \
    if (DOSTORE) { \
        f32x4* _q = (f32x4*)(outr + (TP)); \
        _q[0]=o0; _q[1]=o1; _q[2]=o2; _q[3]=o3; \
        _q[4]=o4; _q[5]=o5; _q[6]=o6; _q[7]=o7; } }

// load one 32-elem phase (8 x float4); TP < 0 (k==0 lookback) -> zeros
#define LOADPH(r0,r1,r2,r3,r4,r5,r6,r7, TP) \
    if ((TP) >= 0) { const f32x4* _p = xr4 + ((TP) >> 2); \
        r0=_p[0]; r1=_p[1]; r2=_p[2]; r3=_p[3]; \
        r4=_p[4]; r5=_p[5]; r6=_p[6]; r7=_p[7]; } \
    else { r0=Z; r1=Z; r2=Z; r3=Z; r4=Z; r5=Z; r6=Z; r7=Z; }

__global__ __launch_bounds__(256) void cpe_lif_kernel(
    const float* __restrict__ x, const float* __restrict__ w,
    const float* __restrict__ cb, const float* __restrict__ gamma,
    const float* __restrict__ beta, const float* __restrict__ rmean,
    const float* __restrict__ rvar, float* __restrict__ out)
{
#pragma clang fp contract(off)   // match np reference rounding op-for-op
    const int u   = blockIdx.x * blockDim.x + threadIdx.x;
    const int row = u >> 4;
    const int k   = u & (K_ - 1);
    const int ch  = row & (C_ - 1);

    // Per-channel constants, numpy-port op order (all fp32, correctly rounded).
    const float w0 = w[ch * 3 + 0], w1 = w[ch * 3 + 1], w2 = w[ch * 3 + 2];
    const float bb = cb[ch];
    const float sq  = sqrtf(rvar[ch] + 1e-5f);
    const float rs  = 1.0f / sq;
    const float inv = gamma[ch] * rs;
    const float add = beta[ch] - rmean[ch] * inv;

    const float*  xr  = x + (size_t)row * T_;
    const f32x4*  xr4 = (const f32x4*)xr;
    float* outr = out + (size_t)row * T_;

    const int t0 = k * CHUNK;
    const int ts = t0 - LOOK;            // -64 for k==0 (handled by guards)

    float xm1 = (k == 0) ? 0.0f : xr[ts - 1];          // conv left halo
    const float xn = (k == K_ - 1) ? 0.0f : xr[t0 + CHUNK];  // right halo peek
    float v = 0.0f;

    f32x4 Z; Z.x = Z.y = Z.z = Z.w = 0.0f;
    f32x4 a0,a1,a2,a3,a4,a5,a6,a7;
    f32x4 b0,b1,b2,b3,b4,b5,b6,b7;
    f32x4 d0,d1,d2,d3,d4,d5,d6,d7;

    // Prologue: 3 phases of loads in flight (96 elements).
    LOADPH(a0,a1,a2,a3,a4,a5,a6,a7, ts)        // phase 0
    LOADPH(b0,b1,b2,b3,b4,b5,b6,b7, ts + 32)   // phase 1
    LOADPH(d0,d1,d2,d3,d4,d5,d6,d7, ts + 64)   // phase 2

    // Phase 0 (lookback, no store; k==0 skips: its buffer is zeros, v must stay 0)
    if (k > 0) { PHASE32(a0,a1,a2,a3,a4,a5,a6,a7, b0.x, ts, false) }
    LOADPH(a0,a1,a2,a3,a4,a5,a6,a7, ts + 96)   // phase 3 -> A

    // Phase 1 (lookback, no store)
    if (k > 0) { PHASE32(b0,b1,b2,b3,b4,b5,b6,b7, d0.x, ts + 32, false) }
    LOADPH(b0,b1,b2,b3,b4,b5,b6,b7, ts + 128)  // phase 4 -> B

    // Phase 2 (t = t0 .. t0+31): store
    PHASE32(d0,d1,d2,d3,d4,d5,d6,d7, a0.x, ts + 64, true)
    LOADPH(d0,d1,d2,d3,d4,d5,d6,d7, ts + 160)  // phase 5 -> D

    // Phases 3..5: store
    PHASE32(a0,a1,a2,a3,a4,a5,a6,a7, b0.x, ts + 96,  true)
    PHASE32(b0,b1,b2,b3,b4,b5,b6,b7, d0.x, ts + 128, true)
    PHASE32(d0,d1,d2,d3,d4,d5,d6,d7, xn,   ts + 160, true)
}

extern "C" void kernel_launch(void* const* d_in, const int* in_sizes, int n_in,
                              void* d_out, int out_size, void* d_ws, size_t ws_size,
                              hipStream_t stream) {
    const float* x     = (const float*)d_in[0];
    const float* w     = (const float*)d_in[1];
    const float* cb    = (const float*)d_in[2];
    const float* gamma = (const float*)d_in[3];
    const float* beta  = (const float*)d_in[4];
    const float* rmean = (const float*)d_in[5];
    const float* rvar  = (const float*)d_in[6];
    float* out = (float*)d_out;

    const int total = B_ * C_ * K_;                    // 131072 threads
    const int block = 256;
    const int grid  = (total + block - 1) / block;     // 512 blocks
    cpe_lif_kernel<<<grid, block, 0, stream>>>(x, w, cb, gamma, beta, rmean, rvar, out);
}